// Round 16
// baseline (123.831 us; speedup 1.0000x reference)
//
#include <hip/hip_runtime.h>
#include <hip/hip_bf16.h>
#include <stdint.h>

typedef __attribute__((ext_vector_type(8))) short short8;
typedef __attribute__((ext_vector_type(4))) float f32x4;

#define NROWS  8192
#define DDIM   256
#define HHEADS 4
#define KTOT   1024
#define BM     256
#define BN     128
#define BK     32
#define NT     (KTOT / BK)        // 32 K-tiles
#define NJOBS  1056               // 8 XCDs x 132
#define BUFE   12288              // elems per K-tile buf: A 8192 + B 4096 (24 KB)

#define SBAR()  __builtin_amdgcn_s_barrier()
#define LGKM0() do { asm volatile("s_waitcnt lgkmcnt(0)" ::: "memory"); \
                     __builtin_amdgcn_sched_barrier(0); } while (0)
#define VMCNT(n) do { asm volatile("s_waitcnt vmcnt(" #n ")" ::: "memory"); \
                      __builtin_amdgcn_sched_barrier(0); } while (0)

__device__ __forceinline__ unsigned short f2bf(float f) {
  union { float f; uint32_t u; } v;
  v.f = f;
  uint32_t u = v.u;
  uint32_t r = (u + 0x7fffu + ((u >> 16) & 1u)) >> 16;
  return (unsigned short)r;
}

// --------------------------------------------------------------------------
// Kernel 1: Y[n, h*256+d] = bf16-normalized per-head scaled rows
// --------------------------------------------------------------------------
__global__ __launch_bounds__(256) void prep_y(const float* __restrict__ x,
                                              const float* __restrict__ av,
                                              unsigned short* __restrict__ Y) {
  __shared__ float a_sh[HHEADS][DDIM];
  __shared__ float red[4][HHEADS];

  const int t = threadIdx.x;
  #pragma unroll
  for (int h = 0; h < HHEADS; ++h) a_sh[h][t] = av[h * DDIM + t];
  __syncthreads();

  const int n = blockIdx.x;
  const float xd = x[(size_t)n * DDIM + t];

  float p[HHEADS], s[HHEADS];
  #pragma unroll
  for (int h = 0; h < HHEADS; ++h) { p[h] = a_sh[h][t] * xd; s[h] = p[h] * p[h]; }

  #pragma unroll
  for (int off = 32; off > 0; off >>= 1) {
    #pragma unroll
    for (int h = 0; h < HHEADS; ++h) s[h] += __shfl_xor(s[h], off, 64);
  }

  const int wave = t >> 6, lane = t & 63;
  if (lane == 0) {
    #pragma unroll
    for (int h = 0; h < HHEADS; ++h) red[wave][h] = s[h];
  }
  __syncthreads();

  #pragma unroll
  for (int h = 0; h < HHEADS; ++h) {
    const float sum = red[0][h] + red[1][h] + red[2][h] + red[3][h];
    const float rn = rsqrtf(fmaxf(sum, 1e-12f));
    Y[(size_t)n * KTOT + h * DDIM + t] = f2bf(p[h] * rn);
  }
}

// --------------------------------------------------------------------------
// stage one 24 KB K-tile (A 256x32 + B 128x32 bf16): 3 global_load_lds(16B)
// per thread (512 threads).  Linear LDS dest; add-rotate swizzle
// slot' = (slot + (row>>1)) & 3 applied on the GLOBAL source (rule #21).
// --------------------------------------------------------------------------
__device__ __forceinline__ void stage_tile(const unsigned short* __restrict__ Y,
                                           unsigned short* buf,
                                           int rowA0, int rowB0, int k0, int tid) {
  #pragma unroll
  for (int i = 0; i < 2; ++i) {                    // A region: 1024 slots
    const int s   = i * 512 + tid;
    const int r   = s >> 2;                        // 0..255
    const int gsl = ((s & 3) + 4 - ((r >> 1) & 3)) & 3;
    const unsigned short* gsrc = Y + (size_t)(rowA0 + r) * KTOT + k0 + gsl * 8;
    __builtin_amdgcn_global_load_lds(
        (const __attribute__((address_space(1))) void*)gsrc,
        (__attribute__((address_space(3))) void*)(buf + s * 8), 16, 0, 0);
  }
  {                                                // B region: 512 slots
    const int s   = tid;
    const int r   = s >> 2;                        // 0..127
    const int gsl = ((s & 3) + 4 - ((r >> 1) & 3)) & 3;
    const unsigned short* gsrc = Y + (size_t)(rowB0 + r) * KTOT + k0 + gsl * 8;
    __builtin_amdgcn_global_load_lds(
        (const __attribute__((address_space(1))) void*)gsrc,
        (__attribute__((address_space(3))) void*)(buf + 8192 + s * 8), 16, 0, 0);
  }
}

// --------------------------------------------------------------------------
// Kernel 2: C = Y*Y^T / 4 on 256x128 tiles (r12 engine: 8 waves, tri-buffer
// BK=32, counted vmcnt, 2 blocks/CU) + SUPERTILE XCD PINNING (r15's +27us
// lever): jobs are grouped so each XCD's 132 jobs share 3-4 MB of panels
// (L2-resident), cutting L2-miss fabric traffic ~811 -> ~200 MB.
//   job (i,j): row-block i (256 rows, 32 of them), col-block j (128 cols),
//   j < 2i+2; straddlers (j >= 2i) skip the mirror.  1056 jobs total.
// Partition: full supers (4 rowb x 8 colb, J<I) split into 56 half-supers
// (2 rowb x 8 colb = 16 jobs, 3MB panels); 8 diagonal supers (20 jobs).
// XCD k (= blockIdx%8, hardware round-robin): halves 7k..7k+6, then diag k.
// --------------------------------------------------------------------------
__global__ __launch_bounds__(512, 4) void gemm_yyt(const unsigned short* __restrict__ Y,
                                                   float* __restrict__ C) {
  __shared__ __attribute__((aligned(16))) unsigned short lds[3 * BUFE];  // 73.7 KB

  // ---- supertile job decode ----
  const int xcd = blockIdx.x & 7;
  const int l   = blockIdx.x >> 3;     // local slot 0..131
  int i, j;
  if (l < 112) {
    // half-super n = xcd*7 + (l>>4); halves enumerated I asc, J asc, h asc:
    // index base for I is I*(I-1); rem = 2*J + h.
    const int n = xcd * 7 + (l >> 4);
    int I = (int)((1.0f + sqrtf(1.0f + 4.0f * (float)n)) * 0.5f);
    while (I * (I - 1) > n) --I;
    while ((I + 1) * I <= n) ++I;
    const int rem = n - I * (I - 1);
    const int J = rem >> 1;
    const int h = rem & 1;
    const int w = l & 15;              // 0..15 within half-super (2x8)
    i = I * 4 + h * 2 + (w >> 3);
    j = J * 8 + (w & 7);
  } else {
    // diagonal super I=J=xcd: 20 jobs, (di,dj) with dj < 2*di+2
    const int w = l - 112;             // 0..19
    int di, dj;
    if      (w < 2)  { di = 0; dj = w; }
    else if (w < 6)  { di = 1; dj = w - 2; }
    else if (w < 12) { di = 2; dj = w - 6; }
    else             { di = 3; dj = w - 12; }
    i = xcd * 4 + di;
    j = xcd * 8 + dj;
  }

  const int rowA0 = i * BM;          // C row block (256)
  const int rowB0 = j * BN;          // C col block (128)
  const bool mirror = (j < 2 * i);

  const int tid  = threadIdx.x;
  const int lane = tid & 63;
  const int wv   = tid >> 6;
  const int wr   = wv >> 1;          // 0..3 (M)
  const int wn   = wv & 1;           // 0..1 (N)
  const int l15  = lane & 15;
  const int lh   = lane >> 4;        // 0..3

  f32x4 acc[4][4];
  #pragma unroll
  for (int m = 0; m < 4; ++m)
    #pragma unroll
    for (int n = 0; n < 4; ++n) acc[m][n] = (f32x4){0.f, 0.f, 0.f, 0.f};

  // prologue: stage K-tiles 0 and 1
  stage_tile(Y, lds + 0,    rowA0, rowB0, 0,  tid);
  stage_tile(Y, lds + BUFE, rowA0, rowB0, BK, tid);
  VMCNT(3);    // tile 0 landed; tile 1's 3 loads may fly
  SBAR();
  __builtin_amdgcn_sched_barrier(0);

  int cur = 0;
  int nx2 = 2 * BUFE;
  short8 af[4], bf[4];

  for (int T = 0; T < NT; ++T) {
    if (T + 2 < NT) stage_tile(Y, lds + nx2, rowA0, rowB0, (T + 2) * BK, tid);

    #pragma unroll
    for (int m = 0; m < 4; ++m) {
      const int r_ = wr * 64 + m * 16 + l15;
      const int sl = (lh + ((r_ >> 1) & 3)) & 3;
      af[m] = *(const short8*)(lds + cur + r_ * 32 + sl * 8);
    }
    #pragma unroll
    for (int n = 0; n < 4; ++n) {
      const int r_ = wn * 64 + n * 16 + l15;
      const int sl = (lh + ((r_ >> 1) & 3)) & 3;
      bf[n] = *(const short8*)(lds + cur + 8192 + r_ * 32 + sl * 8);
    }
    __builtin_amdgcn_sched_barrier(0);
    LGKM0();

    __builtin_amdgcn_s_setprio(1);
    #pragma unroll
    for (int m = 0; m < 4; ++m)
      #pragma unroll
      for (int n = 0; n < 4; ++n)
        acc[m][n] = __builtin_amdgcn_mfma_f32_16x16x32_bf16(
            af[m], bf[n], acc[m][n], 0, 0, 0);
    __builtin_amdgcn_s_setprio(0);
    __builtin_amdgcn_sched_barrier(0);

    if (T < NT - 2)       { VMCNT(3); }   // T+1 landed; T+2 in flight
    else if (T == NT - 2) { VMCNT(0); }   // last prefetch (T+1) landed
    SBAR();

    cur += BUFE; if (cur == 3 * BUFE) cur = 0;
    nx2 += BUFE; if (nx2 == 3 * BUFE) nx2 = 0;
  }

  // ---- straight write (direct; LDS-staging measured neutral, r13) ----
  const int crow0 = rowA0 + wr * 64;
  const int ccol  = rowB0 + wn * 64 + l15;
  #pragma unroll
  for (int m = 0; m < 4; ++m)
    #pragma unroll
    for (int n = 0; n < 4; ++n)
      #pragma unroll
      for (int r = 0; r < 4; ++r) {
        const int row = crow0 + m * 16 + lh * 4 + r;
        C[(size_t)row * NROWS + ccol + n * 16] = acc[m][n][r] * 0.25f;
      }

  // ---- mirror write via LDS transpose (j < 2i only) ----
  if (mirror) {
    float (*tr)[260] = (float(*)[260])lds;   // 32 x 260 f32 = 33.3 KB
    #pragma unroll
    for (int s = 0; s < 4; ++s) {            // col slices of 32
      if (s > 0) SBAR();                     // previous slice readers done
      if (wn == (s >> 1)) {
        const int ns = 2 * (s & 1);
        #pragma unroll
        for (int nn = 0; nn < 2; ++nn)
          #pragma unroll
          for (int m = 0; m < 4; ++m) {
            const int cl  = nn * 16 + l15;                 // 0..31
            const int rl0 = wr * 64 + m * 16 + lh * 4;     // 0..252, %4==0
            *(f32x4*)&tr[cl][rl0] = acc[m][ns + nn];
          }
        LGKM0();                             // my ds_writes visible
      }
      SBAR();
      #pragma unroll
      for (int q = 0; q < 4; ++q) {
        const int idx = q * 512 + tid;       // 0..2047
        const int ii  = idx >> 6;            // 0..31
        const int jj  = (idx & 63) * 4;      // 0..252
        f32x4 v = *(const f32x4*)&tr[ii][jj];
        v *= 0.25f;
        *(f32x4*)(C + (size_t)(rowB0 + s * 32 + ii) * NROWS + rowA0 + jj) = v;
      }
    }
  }
}

// --------------------------------------------------------------------------
extern "C" void kernel_launch(void* const* d_in, const int* in_sizes, int n_in,
                              void* d_out, int out_size, void* d_ws, size_t ws_size,
                              hipStream_t stream) {
  (void)in_sizes; (void)n_in; (void)out_size; (void)ws_size;
  const float* x  = (const float*)d_in[0];   // [8192, 256] f32
  const float* av = (const float*)d_in[1];   // [4, 256] f32
  float* C = (float*)d_out;                  // [8192, 8192] f32
  unsigned short* Y = (unsigned short*)d_ws; // [8192, 1024] bf16 scratch (16 MiB)

  prep_y<<<NROWS, 256, 0, stream>>>(x, av, Y);
  gemm_yyt<<<NJOBS, 512, 0, stream>>>(Y, C);
}

// Round 17
// 87.666 us; speedup vs baseline: 1.4125x; 1.4125x over previous
//
#include <hip/hip_runtime.h>
#include <hip/hip_bf16.h>
#include <stdint.h>

typedef __attribute__((ext_vector_type(4))) int   int4v;
typedef __attribute__((ext_vector_type(8))) int   int8v;
typedef __attribute__((ext_vector_type(4))) float f32x4;

#define NROWS  8192
#define DDIM   256
#define HHEADS 4
#define KTOT   1024               // K in elements (= bytes in fp8)
#define BM     128
#define BN     128
#define BK     128                // fp8 K-tile: one mfma_scale K=128 per tile
#define NT     (KTOT / BK)        // 8 K-tiles
#define BUFB   32768              // bytes per K-tile buf: A 16K + B 16K
#define GRID   2112               // 8 XCDs x 264 slots (32 no-op blocks)

#define SBAR()  __builtin_amdgcn_s_barrier()
#define LGKM0() do { asm volatile("s_waitcnt lgkmcnt(0)" ::: "memory"); \
                     __builtin_amdgcn_sched_barrier(0); } while (0)
#define VMCNT(n) do { asm volatile("s_waitcnt vmcnt(" #n ")" ::: "memory"); \
                      __builtin_amdgcn_sched_barrier(0); } while (0)

// r15's proven supertile->XCD table (supertile = 8x8 tiles; panels L2-fit).
// code = I*8+J (J<=I; diagonal iff code%9==0).  xcd 0-3: 4 full supers
// (256 jobs); xcd 4-7: 3 full + 2 diag (264 jobs).
__constant__ int SUPTAB[8][5] = {
  { 8, 16, 17, 24, -1},
  {25, 26, 32, 33, -1},
  {34, 35, 40, 41, -1},
  {42, 43, 44, 48, -1},
  {49, 50, 51,  0,  9},
  {52, 53, 56, 18, 27},
  {57, 58, 59, 36, 45},
  {60, 61, 62, 54, 63},
};

// --------------------------------------------------------------------------
// Kernel 1: Y[n, h*256+d] = fp8_e4m3( a[h,d]*x[n,d] * rsqrt(max(sum,eps)) )
// HW RNE conversion via v_cvt_pk_fp8_f32 (OCP e4m3 on gfx950).
// --------------------------------------------------------------------------
__global__ __launch_bounds__(256) void prep_y(const float* __restrict__ x,
                                              const float* __restrict__ av,
                                              unsigned char* __restrict__ Y) {
  __shared__ float a_sh[HHEADS][DDIM];
  __shared__ float red[4][HHEADS];

  const int t = threadIdx.x;
  #pragma unroll
  for (int h = 0; h < HHEADS; ++h) a_sh[h][t] = av[h * DDIM + t];
  __syncthreads();

  const int n = blockIdx.x;
  const float xd = x[(size_t)n * DDIM + t];

  float p[HHEADS], s[HHEADS];
  #pragma unroll
  for (int h = 0; h < HHEADS; ++h) { p[h] = a_sh[h][t] * xd; s[h] = p[h] * p[h]; }

  #pragma unroll
  for (int off = 32; off > 0; off >>= 1) {
    #pragma unroll
    for (int h = 0; h < HHEADS; ++h) s[h] += __shfl_xor(s[h], off, 64);
  }

  const int wave = t >> 6, lane = t & 63;
  if (lane == 0) {
    #pragma unroll
    for (int h = 0; h < HHEADS; ++h) red[wave][h] = s[h];
  }
  __syncthreads();

  #pragma unroll
  for (int h = 0; h < HHEADS; ++h) {
    const float sum = red[0][h] + red[1][h] + red[2][h] + red[3][h];
    const float rn = rsqrtf(fmaxf(sum, 1e-12f));
    const float v  = p[h] * rn;
    const int pk = __builtin_amdgcn_cvt_pk_fp8_f32(v, v, 0, false);
    Y[(size_t)n * KTOT + h * DDIM + t] = (unsigned char)(pk & 0xff);
  }
}

// --------------------------------------------------------------------------
// stage one 32 KB fp8 K-tile (A 128x128B + B 128x128B): 4 global_load_lds(16B)
// per thread (512 threads).  Linear LDS dest; XOR slot swizzle
// gsl = (slot&7)^(row&7) on the GLOBAL source (rule #21; r1-proven pattern
// for 128-byte rows, 0 bank conflicts).
// --------------------------------------------------------------------------
__device__ __forceinline__ void stage_tile(const unsigned char* __restrict__ Y,
                                           unsigned char* buf,
                                           int rowA0, int rowB0, int k0, int tid) {
  #pragma unroll
  for (int i = 0; i < 2; ++i) {                    // A region: 1024 slots
    const int s   = i * 512 + tid;
    const int r   = s >> 3;                        // 0..127
    const int gsl = (s & 7) ^ (r & 7);
    const unsigned char* gsrc = Y + (size_t)(rowA0 + r) * KTOT + k0 + gsl * 16;
    __builtin_amdgcn_global_load_lds(
        (const __attribute__((address_space(1))) void*)gsrc,
        (__attribute__((address_space(3))) void*)(buf + s * 16), 16, 0, 0);
  }
  #pragma unroll
  for (int i = 0; i < 2; ++i) {                    // B region: 1024 slots
    const int s   = i * 512 + tid;
    const int r   = s >> 3;
    const int gsl = (s & 7) ^ (r & 7);
    const unsigned char* gsrc = Y + (size_t)(rowB0 + r) * KTOT + k0 + gsl * 16;
    __builtin_amdgcn_global_load_lds(
        (const __attribute__((address_space(1))) void*)gsrc,
        (__attribute__((address_space(3))) void*)(buf + 16384 + s * 16), 16, 0, 0);
  }
}

// --------------------------------------------------------------------------
// Kernel 2: C = Y*Y^T / 4, fp8-MX K=128 MFMA (scales=1.0 -> plain fp8 GEMM
// at the ~4.7 PF rate).  128x128 tiles, 8 waves (4M strips x 2N strips,
// per-wave 32x64 out), BK=128 -> only 8 K-iterations (4x FLOP/iteration vs
// r16 -> per-iteration overhead amortized 4x).  Double-buffered 64 KB LDS,
// 2 blocks/CU.  Supertile XCD pinning from r15 (proven +27us).
// Gram robustness: any internal k-relabeling of the MFMA operand cancels
// because A and B fragments are loaded with identical lane patterns; scales
// all 1.0 make scale-block mapping irrelevant.
// Ledger per K-tile T: ds_read frags from buf[T&1]; lgkm0; SBAR (all waves'
// reads done -> buffer reusable); issue stage(T+2 -> buf[T&1]); MFMA x8;
// vmcnt(4) (T+1's 4 loads landed, T+2's 4 in flight); SBAR.
// --------------------------------------------------------------------------
__global__ __launch_bounds__(512, 4) void gemm_yyt(const unsigned char* __restrict__ Y,
                                                   float* __restrict__ C) {
  __shared__ __attribute__((aligned(16))) unsigned char lds[2 * BUFB];  // 64 KB

  // ---- supertile job decode (r15 verbatim) ----
  const int xcd = blockIdx.x & 7;
  int l = blockIdx.x >> 3;                    // local slot on this XCD
  if (l >= ((xcd < 4) ? 256 : 264)) return;   // 32 pad blocks exit

  int by = 0, bx = 0;
  #pragma unroll 1
  for (int k = 0; k < 5; ++k) {
    const int code = SUPTAB[xcd][k];
    const bool diag = (code % 9) == 0;
    const int cnt = diag ? 36 : 64;
    if (l < cnt) {
      const int I = code >> 3, J = code & 7;
      if (diag) {
        int ty = 0;
        while ((ty + 1) * (ty + 2) / 2 <= l) ++ty;
        const int tx = l - ty * (ty + 1) / 2;
        by = I * 8 + ty; bx = J * 8 + tx;
      } else {
        by = I * 8 + (l >> 3); bx = J * 8 + (l & 7);
      }
      break;
    }
    l -= cnt;
  }

  const int rowA0 = by * BM;
  const int rowB0 = bx * BN;
  const bool mirror = (by != bx);

  const int tid  = threadIdx.x;
  const int lane = tid & 63;
  const int wv   = tid >> 6;      // 0..7
  const int wm   = wv >> 1;       // 0..3  (32-row strip)
  const int wn   = wv & 1;        // 0..1  (64-col strip)
  const int l15  = lane & 15;
  const int lh   = lane >> 4;     // 0..3  (k-chunk of 32)

  f32x4 acc[2][4];
  #pragma unroll
  for (int m = 0; m < 2; ++m)
    #pragma unroll
    for (int n = 0; n < 4; ++n) acc[m][n] = (f32x4){0.f, 0.f, 0.f, 0.f};

  // prologue: stage K-tiles 0 and 1
  stage_tile(Y, lds,        rowA0, rowB0, 0,  tid);
  stage_tile(Y, lds + BUFB, rowA0, rowB0, BK, tid);
  VMCNT(4);    // tile 0 landed; tile 1's 4 loads may fly
  SBAR();
  __builtin_amdgcn_sched_barrier(0);

  for (int T = 0; T < NT; ++T) {
    unsigned char* buf = lds + (T & 1) * BUFB;
    int8v af[2], bf[4];

    // A frags: lane holds row (wm*32 + mt*16 + l15), k-bytes lh*32..+31
    #pragma unroll
    for (int mt = 0; mt < 2; ++mt) {
      const int row = wm * 32 + mt * 16 + l15;
      const unsigned char* base = buf + row * 128;
      const int sl0 = (2 * lh)     ^ (row & 7);
      const int sl1 = (2 * lh + 1) ^ (row & 7);
      const int4v lo = *(const int4v*)(base + sl0 * 16);
      const int4v hi = *(const int4v*)(base + sl1 * 16);
      af[mt] = (int8v){lo[0], lo[1], lo[2], lo[3], hi[0], hi[1], hi[2], hi[3]};
    }
    #pragma unroll
    for (int nt = 0; nt < 4; ++nt) {
      const int row = wn * 64 + nt * 16 + l15;
      const unsigned char* base = buf + 16384 + row * 128;
      const int sl0 = (2 * lh)     ^ (row & 7);
      const int sl1 = (2 * lh + 1) ^ (row & 7);
      const int4v lo = *(const int4v*)(base + sl0 * 16);
      const int4v hi = *(const int4v*)(base + sl1 * 16);
      bf[nt] = (int8v){lo[0], lo[1], lo[2], lo[3], hi[0], hi[1], hi[2], hi[3]};
    }
    LGKM0();
    SBAR();                                   // all waves' reads done

    if (T + 2 < NT) stage_tile(Y, buf, rowA0, rowB0, (T + 2) * BK, tid);

    __builtin_amdgcn_s_setprio(1);
    #pragma unroll
    for (int mt = 0; mt < 2; ++mt)
      #pragma unroll
      for (int nt = 0; nt < 4; ++nt)
        acc[mt][nt] = __builtin_amdgcn_mfma_scale_f32_16x16x128_f8f6f4(
            af[mt], bf[nt], acc[mt][nt],
            0, 0,                      // cbsz/blgp: fp8 e4m3 for A and B
            0, 0x7f7f7f7f,             // scale A = 1.0 (E8M0 127)
            0, 0x7f7f7f7f);            // scale B = 1.0
    __builtin_amdgcn_s_setprio(0);
    __builtin_amdgcn_sched_barrier(0);

    if (T < NT - 2)       { VMCNT(4); }   // T+1 landed; T+2 in flight
    else if (T == NT - 2) { VMCNT(0); }   // last prefetch landed
    SBAR();
  }

  // ---- straight write (direct f32 stores; full lines across the wave) ----
  const int crow0 = rowA0 + wm * 32;
  const int ccol  = rowB0 + wn * 64 + l15;
  #pragma unroll
  for (int mt = 0; mt < 2; ++mt)
    #pragma unroll
    for (int nt = 0; nt < 4; ++nt)
      #pragma unroll
      for (int r = 0; r < 4; ++r) {
        const int row = crow0 + mt * 16 + lh * 4 + r;
        C[(size_t)row * NROWS + ccol + nt * 16] = acc[mt][nt][r] * 0.25f;
      }

  // ---- mirror write via LDS transpose (off-diagonal tiles only) ----
  if (mirror) {
    float (*tr)[132] = (float(*)[132])lds;   // 32 x 132 f32 = 16.9 KB
    #pragma unroll
    for (int s = 0; s < 4; ++s) {            // col slices of 32
      if (s > 0) SBAR();                     // previous slice readers done
      if (wn == (s >> 1)) {
        #pragma unroll
        for (int nn = 0; nn < 2; ++nn) {
          const int nt = 2 * (s & 1) + nn;
          #pragma unroll
          for (int mt = 0; mt < 2; ++mt) {
            const int cl  = nn * 16 + l15;                 // 0..31
            const int rl0 = wm * 32 + mt * 16 + lh * 4;    // 0..124, %4==0
            *(f32x4*)&tr[cl][rl0] = acc[mt][nt];
          }
        }
        LGKM0();                             // my ds_writes visible
      }
      SBAR();
      #pragma unroll
      for (int q = 0; q < 2; ++q) {
        const int idx = q * 512 + tid;       // 0..1023 over 32x32 f32x4
        const int ii  = idx >> 5;            // 0..31
        const int jj  = (idx & 31) * 4;      // 0..124
        f32x4 v = *(const f32x4*)&tr[ii][jj];
        v *= 0.25f;
        *(f32x4*)(C + (size_t)(rowB0 + s * 32 + ii) * NROWS + rowA0 + jj) = v;
      }
    }
  }
}

// --------------------------------------------------------------------------
extern "C" void kernel_launch(void* const* d_in, const int* in_sizes, int n_in,
                              void* d_out, int out_size, void* d_ws, size_t ws_size,
                              hipStream_t stream) {
  (void)in_sizes; (void)n_in; (void)out_size; (void)ws_size;
  const float* x  = (const float*)d_in[0];   // [8192, 256] f32
  const float* av = (const float*)d_in[1];   // [4, 256] f32
  float* C = (float*)d_out;                  // [8192, 8192] f32
  unsigned char* Y = (unsigned char*)d_ws;   // [8192, 1024] fp8 e4m3 (8 MiB)

  prep_y<<<NROWS, 256, 0, stream>>>(x, av, Y);
  gemm_yyt<<<GRID, 512, 0, stream>>>(Y, C);
}